// Round 5
// baseline (430.072 us; speedup 1.0000x reference)
//
#include <hip/hip_runtime.h>
#include <hip/hip_bf16.h>

#define HIDDEN 1024
#define NHEADS 16
#define DKH   64
#define BATCH 2
#define SEQ   2048
#define MTOT  (BATCH*SEQ)   // 4096

using bf16x8 = __attribute__((ext_vector_type(8))) short;
using f32x4  = __attribute__((ext_vector_type(4))) float;
using u16x4  = __attribute__((ext_vector_type(4))) unsigned short;

__device__ __forceinline__ unsigned short f2bf(float f) {
    union { __hip_bfloat16 h; unsigned short u; } v;
    v.h = __float2bfloat16(f);
    return v.u;
}

__device__ __forceinline__ float fexp2(float x) {
#if __has_builtin(__builtin_amdgcn_exp2f)
    return __builtin_amdgcn_exp2f(x);
#else
    return exp2f(x);
#endif
}

__device__ __forceinline__ void gload16(const unsigned short* g, unsigned short* l) {
    __builtin_amdgcn_global_load_lds((const __attribute__((address_space(1))) void*)g,
                                     (__attribute__((address_space(3))) void*)l, 16, 0, 0);
}

#define L2E 1.44269504088896340736f

// ---------------- fused prep: qkv->bf16, W->Wt bf16, bias+mask->fp32 tiled ----------------
// bid [0,12288): cvt_qkv; [12288,13312): cvt_w; [13312,17408): combine bias
__global__ __launch_bounds__(256) void prep(const float4* __restrict__ q,
                                            const float4* __restrict__ k,
                                            const float4* __restrict__ v,
                                            u16x4* __restrict__ qkv_bf,
                                            const float* __restrict__ Wq,
                                            const float* __restrict__ Wk,
                                            const float* __restrict__ Wv,
                                            const float* __restrict__ Wo,
                                            unsigned short* __restrict__ wt,
                                            const float* __restrict__ bias,
                                            const float* __restrict__ mask,
                                            float* __restrict__ biasc) {
    __shared__ float tile[64][65];
    const int bid = blockIdx.x, t = threadIdx.x;
    if (bid < 12288) {
        int i = bid * 256 + t;
        const int per = MTOT * HIDDEN / 4;
        const float4* src; int tt;
        if (i < per)            { src = q; tt = 0; }
        else if (i < 2 * per)   { src = k; tt = 1; }
        else                    { src = v; tt = 2; }
        float4 f = src[i - tt * per];
        u16x4 o; o.x = f2bf(f.x); o.y = f2bf(f.y); o.z = f2bf(f.z); o.w = f2bf(f.w);
        qkv_bf[i] = o;
    } else if (bid < 13312) {
        int r = bid - 12288;
        const int z = r >> 8; r &= 255;
        const int kb = (r >> 4) * 64, nb = (r & 15) * 64;
        const float* W = (z == 0) ? Wq : (z == 1) ? Wk : (z == 2) ? Wv : Wo;
        unsigned short* out = wt + (size_t)z * HIDDEN * HIDDEN;
        #pragma unroll
        for (int i = 0; i < 16; i++) {
            int idx = i * 256 + t; int rr = idx >> 6, c = idx & 63;
            tile[rr][c] = W[(size_t)(kb + rr) * HIDDEN + nb + c];
        }
        __syncthreads();
        #pragma unroll
        for (int i = 0; i < 16; i++) {
            int idx = i * 256 + t; int n = idx >> 6, kk = idx & 63;
            out[(size_t)(nb + n) * HIDDEN + kb + kk] = f2bf(tile[kk][n]);
        }
    } else {
        int cb = bid - 13312;   // 0..4095
        const int kvb = cb & 63, qt = (cb >> 6) & 31, b = cb >> 11;
        const int qq = t >> 2, kvc = (t & 3) * 8;
        const float* bp = bias + ((size_t)b * SEQ + qt * 64 + qq) * SEQ + kvb * 32 + kvc;
        const float* mp = mask + ((size_t)b * SEQ + qt * 64 + qq) * SEQ + kvb * 32 + kvc;
        float4 b0 = *(const float4*)bp, b1 = *(const float4*)(bp + 4);
        float4 m0 = *(const float4*)mp, m1 = *(const float4*)(mp + 4);
        float* op = biasc + ((size_t)(b * 32 + qt) * 64 + kvb) * 2048 + t * 8;
        *(float4*)op = make_float4((b0.x + m0.x) * L2E, (b0.y + m0.y) * L2E,
                                   (b0.z + m0.z) * L2E, (b0.w + m0.w) * L2E);
        *(float4*)(op + 4) = make_float4((b1.x + m1.x) * L2E, (b1.y + m1.y) * L2E,
                                         (b1.z + m1.z) * L2E, (b1.w + m1.w) * L2E);
    }
}

// ---------------- 128x128 bf16 MFMA GEMM core ----------------
__device__ __forceinline__ void gemm_core_128(const unsigned short* __restrict__ X,
                                              const unsigned short* __restrict__ Wt,
                                              unsigned short* smem,
                                              int mbase, int nbase, f32x4 acc[4][4]) {
    const int tid = threadIdx.x, w = tid >> 6, ln = tid & 63;
    const int qr = (w >> 1) * 64, qc = (w & 1) * 64;
    const int g = ln >> 4, c16 = ln & 15;
    #pragma unroll
    for (int rt = 0; rt < 4; rt++)
        #pragma unroll
        for (int ct = 0; ct < 4; ct++) acc[rt][ct] = (f32x4){0.f, 0.f, 0.f, 0.f};

    for (int kk = 0; kk < HIDDEN; kk += 64) {
        __syncthreads();
        #pragma unroll
        for (int pass = 0; pass < 4; pass++) {
            int L = pass * 256 + tid;
            int r = L >> 3, c = (L & 7) ^ (r & 7);              // XOR swizzle
            gload16(X  + (size_t)(mbase + r) * HIDDEN + kk + c * 8,
                    smem + (size_t)(pass * 256 + w * 64) * 8);
            gload16(Wt + (size_t)(nbase + r) * HIDDEN + kk + c * 8,
                    smem + 8192 + (size_t)(pass * 256 + w * 64) * 8);
        }
        __syncthreads();
        #pragma unroll
        for (int ks = 0; ks < 2; ks++) {
            bf16x8 af[4], bfr[4];
            #pragma unroll
            for (int rt = 0; rt < 4; rt++) {
                int r = qr + rt * 16 + c16;
                int ch = (g + ks * 4) ^ (r & 7);
                af[rt] = *(const bf16x8*)(smem + (size_t)(r * 8 + ch) * 8);
            }
            #pragma unroll
            for (int ct = 0; ct < 4; ct++) {
                int n = qc + ct * 16 + c16;
                int ch = (g + ks * 4) ^ (n & 7);
                bfr[ct] = *(const bf16x8*)(smem + 8192 + (size_t)(n * 8 + ch) * 8);
            }
            #pragma unroll
            for (int rt = 0; rt < 4; rt++)
                #pragma unroll
                for (int ct = 0; ct < 4; ct++)
                    acc[rt][ct] = __builtin_amdgcn_mfma_f32_16x16x32_bf16(af[rt], bfr[ct], acc[rt][ct], 0, 0, 0);
        }
    }
    __syncthreads();
}

// ---------------- projections ----------------
// q -> qh [bh][q][64] (scaled by 0.125*log2e)
// k -> khp [bh][tile32][ks2][kvsub2][x16][32]  (MFMA-A fragment order, S^T row perm)
// v -> vtt [bh][tile32][d64][kv32]
__global__ __launch_bounds__(256, 2) void proj_gemm(const unsigned short* __restrict__ Xall,
                                                    const unsigned short* __restrict__ Wtall,
                                                    const float* __restrict__ bq,
                                                    const float* __restrict__ bk,
                                                    const float* __restrict__ bv,
                                                    unsigned short* __restrict__ qh,
                                                    unsigned short* __restrict__ khp,
                                                    unsigned short* __restrict__ vtt) {
    __shared__ __align__(16) unsigned short smem[18432];
    const int z = blockIdx.z;
    const unsigned short* X  = Xall  + (size_t)z * MTOT * HIDDEN;
    const unsigned short* Wt = Wtall + (size_t)z * HIDDEN * HIDDEN;
    const float* bias = (z == 0) ? bq : (z == 1) ? bk : bv;
    const int mbase = blockIdx.x * 128, nbase = blockIdx.y * 128;
    const int tid = threadIdx.x, w = tid >> 6, ln = tid & 63;
    const int qr = (w >> 1) * 64, qc = (w & 1) * 64;
    const int g = ln >> 4, c16 = ln & 15;

    f32x4 acc[4][4];
    gemm_core_128(X, Wt, smem, mbase, nbase, acc);

    const float scale = (z == 0) ? (0.125f * L2E) : 1.0f;
    float bias_v[4];
    #pragma unroll
    for (int ct = 0; ct < 4; ct++) bias_v[ct] = bias[nbase + qc + ct * 16 + c16];

    unsigned short* eld = smem + w * 4608;   // 64x72 per wave
    #pragma unroll
    for (int rt = 0; rt < 4; rt++)
        #pragma unroll
        for (int ct = 0; ct < 4; ct++)
            #pragma unroll
            for (int r4 = 0; r4 < 4; r4++) {
                int row_l = rt * 16 + g * 4 + r4;    // pos (local)
                int col_l = ct * 16 + c16;           // n (local)
                float val = (acc[rt][ct][r4] + bias_v[ct]) * scale;
                if (z == 2) eld[col_l * 72 + row_l] = f2bf(val);  // [d][pos]
                else        eld[row_l * 72 + col_l] = f2bf(val);  // [pos][d]
            }
    __syncthreads();

    const int b = mbase >> 11;
    const int pos0 = (mbase & 2047) + qr;   // multiple of 64
    const int h = (nbase + qc) >> 6;
    const int bh = b * NHEADS + h;
    if (z == 0) {
        const int row8 = ln >> 3, col8 = (ln & 7) * 8;
        unsigned short* dst0 = qh + ((size_t)bh * SEQ + pos0) * DKH;
        #pragma unroll
        for (int j = 0; j < 8; j++) {
            int row = j * 8 + row8;
            *(bf16x8*)(dst0 + row * 64 + col8) = *(const bf16x8*)&eld[row * 72 + col8];
        }
    } else if (z == 1) {
        unsigned short* base = khp + ((size_t)bh * 64 + (pos0 >> 5)) * 2048;
        const int x = ln >> 2;
        #pragma unroll
        for (int j = 0; j < 8; j++) {
            int kvl  = (x >> 2) * 8 + (j & 1) * 4 + (x & 3);
            int row  = (j >> 2) * 32 + kvl;               // pos (local)
            int dcol = ((j >> 1) & 1) * 32 + (ln & 3) * 8;
            *(bf16x8*)(base + j * 512 + ln * 8) = *(const bf16x8*)&eld[row * 72 + dcol];
        }
    } else {
        unsigned short* base = vtt + ((size_t)bh * 64 + (pos0 >> 5)) * 2048;
        #pragma unroll
        for (int j = 0; j < 8; j++) {
            int o = j * 512 + ln * 8;
            int tloc = o >> 11;
            int dl = (o & 2047) >> 5;
            int kvo = (ln & 3) * 8;
            *(bf16x8*)(base + o) = *(const bf16x8*)&eld[dl * 72 + tloc * 32 + kvo];
        }
    }
}

// ---------------- attention: 16-q waves, software-pipelined fragment loads ----------------
// Block = 32 q x full kv; 4 waves = 2 qg (16 q) x 2 kg (1024 kv). Per wave-iter:
// 32-kv tile: 4 QK + 4 PV MFMAs, 8 exp2, fp32 bias init. K-fragments + bias are
// double-buffered one iteration ahead; V issued at body top (consumed post-exp).
// Unnormalized exp2 (scores bounded); l summed per lane, reduced once at end.
__global__ __launch_bounds__(256, 4) void attn(const unsigned short* __restrict__ qh,
                                               const unsigned short* __restrict__ khp,
                                               const unsigned short* __restrict__ vtt,
                                               const float* __restrict__ biasc,
                                               unsigned short* __restrict__ ctx) {
    __shared__ __align__(16) float red[2][1024];          // [qg][dt*256 + ln*4]
    __shared__ float lred[2][16];
    __shared__ __align__(16) unsigned short tr[2][16][72];
    const int tid = threadIdx.x;
    const int w = tid >> 6, ln = tid & 63;
    const int quad = ln >> 4, c16 = ln & 15;
    const int qg = w & 1, kg = w >> 1;
    // XCD swizzle: each XCD gets 16 (b,qblk) pairs x 16 heads (bias tile L2 reuse)
    const int bid = blockIdx.x;
    const int xcd = bid & 7, s = bid >> 3;   // s in 0..255
    const int pair = xcd * 16 + (s >> 4);    // 0..127
    const int h = s & 15;
    const int b = pair >> 6, qblk = pair & 63;
    const int bh = b * NHEADS + h;
    const int qrow = qblk * 32 + qg * 16 + c16;

    bf16x8 qf0, qf1;
    {
        const unsigned short* qp = qh + ((size_t)bh * SEQ + qrow) * DKH + quad * 8;
        qf0 = *(const bf16x8*)qp;
        qf1 = *(const bf16x8*)(qp + 32);
    }
    const unsigned short* kbase = khp + ((size_t)bh * 64 + kg * 32) * 2048 + c16 * 32 + quad * 8;
    const unsigned short* vbase = vtt + ((size_t)bh * 64 + kg * 32) * 2048 + c16 * 32 + quad * 8;
    const float* bbase = biasc + ((size_t)(b * 32 + (qblk >> 1)) * 64 + kg * 32) * 2048
                       + ((qblk & 1) * 32 + qg * 16 + c16) * 32 + quad * 8;

    f32x4 accv[4];
    #pragma unroll
    for (int dt = 0; dt < 4; dt++) accv[dt] = (f32x4){0.f, 0.f, 0.f, 0.f};
    float lacc = 0.f;

    // prologue: stage j=0 K-fragments + bias
    bf16x8 k00 = *(const bf16x8*)(kbase);
    bf16x8 k01 = *(const bf16x8*)(kbase + 512);
    bf16x8 k10 = *(const bf16x8*)(kbase + 1024);
    bf16x8 k11 = *(const bf16x8*)(kbase + 1536);
    f32x4  bi0 = *(const f32x4*)(bbase);
    f32x4  bi1 = *(const f32x4*)(bbase + 4);

    #pragma unroll 2
    for (int j = 0; j < 32; j++) {
        const int jn = (j < 31) ? (j + 1) : 31;
        const unsigned short* kn = kbase + jn * 2048;
        const float* bn = bbase + jn * 2048;
        // next-iteration prefetch (K + bias)
        bf16x8 nk00 = *(const bf16x8*)(kn);
        bf16x8 nk01 = *(const bf16x8*)(kn + 512);
        bf16x8 nk10 = *(const bf16x8*)(kn + 1024);
        bf16x8 nk11 = *(const bf16x8*)(kn + 1536);
        f32x4  nbi0 = *(const f32x4*)(bn);
        f32x4  nbi1 = *(const f32x4*)(bn + 4);
        // current V (used after exp — in flight during QK+softmax)
        const unsigned short* vp = vbase + j * 2048;
        bf16x8 vf0 = *(const bf16x8*)(vp);
        bf16x8 vf1 = *(const bf16x8*)(vp + 512);
        bf16x8 vf2 = *(const bf16x8*)(vp + 1024);
        bf16x8 vf3 = *(const bf16x8*)(vp + 1536);

        // S^T = K.Q^T + bias (C: col=q=c16, row=kv quad*4-group)
        f32x4 s0 = bi0, s1 = bi1;
        s0 = __builtin_amdgcn_mfma_f32_16x16x32_bf16(k00, qf0, s0, 0, 0, 0);
        s0 = __builtin_amdgcn_mfma_f32_16x16x32_bf16(k10, qf1, s0, 0, 0, 0);
        s1 = __builtin_amdgcn_mfma_f32_16x16x32_bf16(k01, qf0, s1, 0, 0, 0);
        s1 = __builtin_amdgcn_mfma_f32_16x16x32_bf16(k11, qf1, s1, 0, 0, 0);

        #pragma unroll
        for (int r = 0; r < 4; r++) { s0[r] = fexp2(s0[r]); s1[r] = fexp2(s1[r]); }
        lacc += ((s0[0] + s0[1]) + (s0[2] + s0[3])) + ((s1[0] + s1[1]) + (s1[2] + s1[3]));

        union { bf16x8 v; __hip_bfloat162 hh[4]; } pu;
        pu.hh[0] = __float22bfloat162_rn(make_float2(s0[0], s0[1]));
        pu.hh[1] = __float22bfloat162_rn(make_float2(s0[2], s0[3]));
        pu.hh[2] = __float22bfloat162_rn(make_float2(s1[0], s1[1]));
        pu.hh[3] = __float22bfloat162_rn(make_float2(s1[2], s1[3]));

        accv[0] = __builtin_amdgcn_mfma_f32_16x16x32_bf16(vf0, pu.v, accv[0], 0, 0, 0);
        accv[1] = __builtin_amdgcn_mfma_f32_16x16x32_bf16(vf1, pu.v, accv[1], 0, 0, 0);
        accv[2] = __builtin_amdgcn_mfma_f32_16x16x32_bf16(vf2, pu.v, accv[2], 0, 0, 0);
        accv[3] = __builtin_amdgcn_mfma_f32_16x16x32_bf16(vf3, pu.v, accv[3], 0, 0, 0);

        k00 = nk00; k01 = nk01; k10 = nk10; k11 = nk11;
        bi0 = nbi0; bi1 = nbi1;
    }

    // ---- cross-kv-group reduction ----
    if (kg == 1) {
        float* dst = red[qg];
        #pragma unroll
        for (int dt = 0; dt < 4; dt++)
            *(f32x4*)(dst + dt * 256 + ln * 4) = accv[dt];
        float l = lacc;
        l += __shfl_xor(l, 16);
        l += __shfl_xor(l, 32);
        if (ln < 16) lred[qg][ln] = l;
    }
    __syncthreads();
    if (kg == 0) {
        float l = lacc;
        l += __shfl_xor(l, 16);
        l += __shfl_xor(l, 32);
        l += lred[qg][c16];
        float inv = 1.0f / l;
        #pragma unroll
        for (int dt = 0; dt < 4; dt++) {
            accv[dt] += *(const f32x4*)(red[qg] + dt * 256 + ln * 4);
            #pragma unroll
            for (int r = 0; r < 4; r += 2) {
                union { __hip_bfloat162 hh; unsigned int u; } pk;
                pk.hh = __float22bfloat162_rn(make_float2(accv[dt][r] * inv,
                                                         accv[dt][r + 1] * inv));
                *(unsigned int*)&tr[qg][c16][dt * 16 + quad * 4 + r] = pk.u;
            }
        }
    }
    __syncthreads();
    if (kg == 0) {
        int qq = ln >> 2, dc = (ln & 3) * 16;
        const unsigned short* srcp = &tr[qg][qq][dc];
        unsigned short* dstp = ctx + ((size_t)b * SEQ + qblk * 32 + qg * 16 + qq) * HIDDEN
                             + h * 64 + dc;
        *(bf16x8*)dstp       = *(const bf16x8*)srcp;
        *(bf16x8*)(dstp + 8) = *(const bf16x8*)(srcp + 8);
    }
}

// ---------------- output projection ----------------
__global__ __launch_bounds__(256, 2) void outproj(const unsigned short* __restrict__ X,
                                                  const unsigned short* __restrict__ Wt,
                                                  const float* __restrict__ bo,
                                                  float* __restrict__ out) {
    __shared__ __align__(16) unsigned short smem[16384];
    const int mbase = blockIdx.x * 128, nbase = blockIdx.y * 128;
    const int tid = threadIdx.x, w = tid >> 6, ln = tid & 63;
    const int qr = (w >> 1) * 64, qc = (w & 1) * 64;
    const int g = ln >> 4, c16 = ln & 15;

    f32x4 acc[4][4];
    gemm_core_128(X, Wt, smem, mbase, nbase, acc);

    float bo_v[4];
    #pragma unroll
    for (int ct = 0; ct < 4; ct++) bo_v[ct] = bo[nbase + qc + ct * 16 + c16];
    #pragma unroll
    for (int rt = 0; rt < 4; rt++)
        #pragma unroll
        for (int ct = 0; ct < 4; ct++)
            #pragma unroll
            for (int r4 = 0; r4 < 4; r4++)
                out[(size_t)(mbase + qr + rt * 16 + g * 4 + r4) * HIDDEN + nbase + qc + ct * 16 + c16]
                    = acc[rt][ct][r4] + bo_v[ct];
}

// ---------------- launch ----------------
extern "C" void kernel_launch(void* const* d_in, const int* in_sizes, int n_in,
                              void* d_out, int out_size, void* d_ws, size_t ws_size,
                              hipStream_t stream) {
    const float* q    = (const float*)d_in[0];
    const float* k    = (const float*)d_in[1];
    const float* v    = (const float*)d_in[2];
    const float* bias = (const float*)d_in[3];
    const float* mask = (const float*)d_in[4];
    const float* Wq   = (const float*)d_in[5];
    const float* bq   = (const float*)d_in[6];
    const float* Wk   = (const float*)d_in[7];
    const float* bk   = (const float*)d_in[8];
    const float* Wv   = (const float*)d_in[9];
    const float* bv   = (const float*)d_in[10];
    const float* Wo   = (const float*)d_in[11];
    const float* bo   = (const float*)d_in[12];

    char* ws = (char*)d_ws;
    unsigned short* qkv_bf = (unsigned short*)(ws);              // 24 MB
    unsigned short* wt     = (unsigned short*)(ws + 25165824);   // 8 MB
    unsigned short* qh     = (unsigned short*)(ws + 33554432);   // 8 MB
    unsigned short* khp    = (unsigned short*)(ws + 41943040);   // 8 MB
    unsigned short* vtt    = (unsigned short*)(ws + 50331648);   // 8 MB
    unsigned short* ctx    = (unsigned short*)(ws + 58720256);   // 8 MB
    float*          biasc  = (float*)(ws + 67108864);            // 32 MB fp32 tiled
    // total ws use: 100,663,296 bytes

    prep<<<17408, 256, 0, stream>>>((const float4*)q, (const float4*)k, (const float4*)v,
                                    (u16x4*)qkv_bf, Wq, Wk, Wv, Wo, wt, bias, mask, biasc);
    proj_gemm<<<dim3(32, 8, 3), 256, 0, stream>>>(qkv_bf, wt, bq, bk, bv, qh, khp, vtt);
    attn<<<2048, 256, 0, stream>>>(qh, khp, vtt, biasc, ctx);
    outproj<<<dim3(32, 8), 256, 0, stream>>>(ctx, wt + (size_t)3 * HIDDEN * HIDDEN, bo,
                                             (float*)d_out);
}

// Round 6
// 277.494 us; speedup vs baseline: 1.5498x; 1.5498x over previous
//
#include <hip/hip_runtime.h>
#include <hip/hip_bf16.h>

#define HIDDEN 1024
#define NHEADS 16
#define DKH   64
#define BATCH 2
#define SEQ   2048
#define MTOT  (BATCH*SEQ)   // 4096

using bf16x8 = __attribute__((ext_vector_type(8))) short;
using f32x4  = __attribute__((ext_vector_type(4))) float;
using u16x4  = __attribute__((ext_vector_type(4))) unsigned short;

__device__ __forceinline__ unsigned short f2bf(float f) {
    union { __hip_bfloat16 h; unsigned short u; } v;
    v.h = __float2bfloat16(f);
    return v.u;
}

__device__ __forceinline__ float asfloat(unsigned int u) {
    union { unsigned int u; float f; } v; v.u = u; return v.f;
}

__device__ __forceinline__ float fexp2(float x) {
#if __has_builtin(__builtin_amdgcn_exp2f)
    return __builtin_amdgcn_exp2f(x);
#else
    return exp2f(x);
#endif
}

// async global->LDS, 16B per lane. LDS ptr must be wave-uniform (HW adds lane*16).
__device__ __forceinline__ void gload16(const unsigned short* g, unsigned short* l) {
    __builtin_amdgcn_global_load_lds((const __attribute__((address_space(1))) void*)g,
                                     (__attribute__((address_space(3))) void*)l, 16, 0, 0);
}

#define L2E 1.44269504088896340736f

// ---------------- fused prep ----------------
// bid [0,12288): qkv->bf16; [12288,13312): W->Wt bf16; [13312,17408): bias+mask ->
// biasf bf16 fragment-tiled: [b][qg128][t64][lane64*8] where lane ln holds
// q = qg*16 + (ln&15), kv = t*32 + (ln>>4)*8 + i (i=0..7), value (bias+mask)*log2e.
__global__ __launch_bounds__(256) void prep(const float4* __restrict__ q,
                                            const float4* __restrict__ k,
                                            const float4* __restrict__ v,
                                            u16x4* __restrict__ qkv_bf,
                                            const float* __restrict__ Wq,
                                            const float* __restrict__ Wk,
                                            const float* __restrict__ Wv,
                                            const float* __restrict__ Wo,
                                            unsigned short* __restrict__ wt,
                                            const float* __restrict__ bias,
                                            const float* __restrict__ mask,
                                            unsigned short* __restrict__ biasf) {
    __shared__ float tile[64][65];
    const int bid = blockIdx.x, t = threadIdx.x;
    if (bid < 12288) {
        int i = bid * 256 + t;
        const int per = MTOT * HIDDEN / 4;
        const float4* src; int tt;
        if (i < per)            { src = q; tt = 0; }
        else if (i < 2 * per)   { src = k; tt = 1; }
        else                    { src = v; tt = 2; }
        float4 f = src[i - tt * per];
        u16x4 o; o.x = f2bf(f.x); o.y = f2bf(f.y); o.z = f2bf(f.z); o.w = f2bf(f.w);
        qkv_bf[i] = o;
    } else if (bid < 13312) {
        int r = bid - 12288;
        const int z = r >> 8; r &= 255;
        const int kb = (r >> 4) * 64, nb = (r & 15) * 64;
        const float* W = (z == 0) ? Wq : (z == 1) ? Wk : (z == 2) ? Wv : Wo;
        unsigned short* out = wt + (size_t)z * HIDDEN * HIDDEN;
        #pragma unroll
        for (int i = 0; i < 16; i++) {
            int idx = i * 256 + t; int rr = idx >> 6, c = idx & 63;
            tile[rr][c] = W[(size_t)(kb + rr) * HIDDEN + nb + c];
        }
        __syncthreads();
        #pragma unroll
        for (int i = 0; i < 16; i++) {
            int idx = i * 256 + t; int n = idx >> 6, kk = idx & 63;
            out[(size_t)(nb + n) * HIDDEN + kb + kk] = f2bf(tile[kk][n]);
        }
    } else {
        const int cb = bid - 13312;   // 0..4095
        const int tblk = cb & 15, g = (cb >> 4) & 127, b = cb >> 11;
        const int tsub = t >> 6, ln = t & 63;
        const int c16 = ln & 15, quad = ln >> 4;
        const int tt_ = tblk * 4 + tsub;
        const int qq = g * 16 + c16;
        const int kv0 = tt_ * 32 + quad * 8;
        const float* bp = bias + ((size_t)b * SEQ + qq) * SEQ + kv0;
        const float* mp = mask + ((size_t)b * SEQ + qq) * SEQ + kv0;
        float4 b0 = *(const float4*)bp, b1 = *(const float4*)(bp + 4);
        float4 m0 = *(const float4*)mp, m1 = *(const float4*)(mp + 4);
        union { bf16x8 v; __hip_bfloat162 hh[4]; } o;
        o.hh[0] = __float22bfloat162_rn(make_float2((b0.x + m0.x) * L2E, (b0.y + m0.y) * L2E));
        o.hh[1] = __float22bfloat162_rn(make_float2((b0.z + m0.z) * L2E, (b0.w + m0.w) * L2E));
        o.hh[2] = __float22bfloat162_rn(make_float2((b1.x + m1.x) * L2E, (b1.y + m1.y) * L2E));
        o.hh[3] = __float22bfloat162_rn(make_float2((b1.z + m1.z) * L2E, (b1.w + m1.w) * L2E));
        *(bf16x8*)(biasf + (((size_t)b * 128 + g) * 64 + tt_) * 512 + ln * 8) = o.v;
    }
}

// ---------------- 128x128 bf16 MFMA GEMM core ----------------
__device__ __forceinline__ void gemm_core_128(const unsigned short* __restrict__ X,
                                              const unsigned short* __restrict__ Wt,
                                              unsigned short* smem,
                                              int mbase, int nbase, f32x4 acc[4][4]) {
    const int tid = threadIdx.x, w = tid >> 6, ln = tid & 63;
    const int qr = (w >> 1) * 64, qc = (w & 1) * 64;
    const int g = ln >> 4, c16 = ln & 15;
    #pragma unroll
    for (int rt = 0; rt < 4; rt++)
        #pragma unroll
        for (int ct = 0; ct < 4; ct++) acc[rt][ct] = (f32x4){0.f, 0.f, 0.f, 0.f};

    for (int kk = 0; kk < HIDDEN; kk += 64) {
        __syncthreads();
        #pragma unroll
        for (int pass = 0; pass < 4; pass++) {
            int L = pass * 256 + tid;
            int r = L >> 3, c = (L & 7) ^ (r & 7);              // XOR swizzle
            gload16(X  + (size_t)(mbase + r) * HIDDEN + kk + c * 8,
                    smem + (size_t)(pass * 256 + w * 64) * 8);
            gload16(Wt + (size_t)(nbase + r) * HIDDEN + kk + c * 8,
                    smem + 8192 + (size_t)(pass * 256 + w * 64) * 8);
        }
        __syncthreads();
        #pragma unroll
        for (int ks = 0; ks < 2; ks++) {
            bf16x8 af[4], bfr[4];
            #pragma unroll
            for (int rt = 0; rt < 4; rt++) {
                int r = qr + rt * 16 + c16;
                int ch = (g + ks * 4) ^ (r & 7);
                af[rt] = *(const bf16x8*)(smem + (size_t)(r * 8 + ch) * 8);
            }
            #pragma unroll
            for (int ct = 0; ct < 4; ct++) {
                int n = qc + ct * 16 + c16;
                int ch = (g + ks * 4) ^ (n & 7);
                bfr[ct] = *(const bf16x8*)(smem + 8192 + (size_t)(n * 8 + ch) * 8);
            }
            #pragma unroll
            for (int rt = 0; rt < 4; rt++)
                #pragma unroll
                for (int ct = 0; ct < 4; ct++)
                    acc[rt][ct] = __builtin_amdgcn_mfma_f32_16x16x32_bf16(af[rt], bfr[ct], acc[rt][ct], 0, 0, 0);
        }
    }
    __syncthreads();
}

// ---------------- projections ----------------
// q -> qh  [bh][q][64] (scaled by 0.125*log2e)
// k -> khs [bh][t64][ks2][kvs2][lane64*8]: lane ln holds
//          K[kv = t*32 + (c16>>2)*8 + kvs*4 + (c16&3)][d = ks*32 + quad*8 + i]
//          (kv permutation makes S^T C-rows == PV B-operand rows)
// v -> vts [bh][t64][dt4][lane64*8]: lane ln holds V[kv = t*32 + quad*8 + i][d = dt*16 + c16]
__global__ __launch_bounds__(256, 2) void proj_gemm(const unsigned short* __restrict__ Xall,
                                                    const unsigned short* __restrict__ Wtall,
                                                    const float* __restrict__ bq,
                                                    const float* __restrict__ bk,
                                                    const float* __restrict__ bv,
                                                    unsigned short* __restrict__ qh,
                                                    unsigned short* __restrict__ khs,
                                                    unsigned short* __restrict__ vts) {
    __shared__ __align__(16) unsigned short smem[18432];
    const int z = blockIdx.z;
    const unsigned short* X  = Xall  + (size_t)z * MTOT * HIDDEN;
    const unsigned short* Wt = Wtall + (size_t)z * HIDDEN * HIDDEN;
    const float* bias = (z == 0) ? bq : (z == 1) ? bk : bv;
    const int mbase = blockIdx.x * 128, nbase = blockIdx.y * 128;
    const int tid = threadIdx.x, w = tid >> 6, ln = tid & 63;
    const int qr = (w >> 1) * 64, qc = (w & 1) * 64;
    const int g = ln >> 4, c16 = ln & 15;

    f32x4 acc[4][4];
    gemm_core_128(X, Wt, smem, mbase, nbase, acc);

    const float scale = (z == 0) ? (0.125f * L2E) : 1.0f;
    float bias_v[4];
    #pragma unroll
    for (int ct = 0; ct < 4; ct++) bias_v[ct] = bias[nbase + qc + ct * 16 + c16];

    unsigned short* eld = smem + w * 4608;   // 64x72 per wave
    #pragma unroll
    for (int rt = 0; rt < 4; rt++)
        #pragma unroll
        for (int ct = 0; ct < 4; ct++)
            #pragma unroll
            for (int r4 = 0; r4 < 4; r4++) {
                int row_l = rt * 16 + g * 4 + r4;    // pos (local)
                int col_l = ct * 16 + c16;           // n (local)
                float val = (acc[rt][ct][r4] + bias_v[ct]) * scale;
                if (z == 2) eld[col_l * 72 + row_l] = f2bf(val);  // [d][pos]
                else        eld[row_l * 72 + col_l] = f2bf(val);  // [pos][d]
            }
    __syncthreads();

    const int b = mbase >> 11;
    const int pos0 = (mbase & 2047) + qr;   // multiple of 64
    const int h = (nbase + qc) >> 6;
    const int bh = b * NHEADS + h;
    if (z == 0) {
        const int row8 = ln >> 3, col8 = (ln & 7) * 8;
        unsigned short* dst0 = qh + ((size_t)bh * SEQ + pos0) * DKH;
        #pragma unroll
        for (int j = 0; j < 8; j++) {
            int row = j * 8 + row8;
            *(bf16x8*)(dst0 + row * 64 + col8) = *(const bf16x8*)&eld[row * 72 + col8];
        }
    } else if (z == 1) {
        unsigned short* base = khs + ((size_t)bh * 64 + (pos0 >> 5)) * 2048;
        const int kvp = (c16 >> 2) * 8 + (c16 & 3);
        #pragma unroll
        for (int j = 0; j < 8; j++) {
            int tloc = j >> 2, ks = (j >> 1) & 1, kvs = j & 1;
            int kvl = tloc * 32 + kvp + kvs * 4;
            *(bf16x8*)(base + tloc * 2048 + ks * 1024 + kvs * 512 + ln * 8)
                = *(const bf16x8*)&eld[kvl * 72 + ks * 32 + g * 8];
        }
    } else {
        unsigned short* base = vts + ((size_t)bh * 64 + (pos0 >> 5)) * 2048;
        #pragma unroll
        for (int j = 0; j < 8; j++) {
            int tloc = j >> 2, dt = j & 3;
            *(bf16x8*)(base + tloc * 2048 + dt * 512 + ln * 8)
                = *(const bf16x8*)&eld[(dt * 16 + c16) * 72 + tloc * 32 + g * 8];
        }
    }
}

// ---------------- attention: LDS-staged K/V (m97 2-barrier K-loop) ----------------
// Block = 128 q x 2048 kv, 4 waves x 32 q. Per 128-kv tile: stage K 16KB + V 16KB
// via async global_load_lds (lane-linear, conflict-free), all 4 waves consume via
// lane-linear ds_read_b128. Bias: bf16 fragment-tiled, register-prefetched 1 tile
// ahead (drained by the staging barrier's vmcnt(0)). Unnormalized exp2 softmax.
__global__ __launch_bounds__(256, 2) void attn(const unsigned short* __restrict__ qh,
                                               const unsigned short* __restrict__ khs,
                                               const unsigned short* __restrict__ vts,
                                               const unsigned short* __restrict__ biasf,
                                               unsigned short* __restrict__ ctx) {
    __shared__ __align__(16) unsigned short smem[16384];   // K 8192 | V 8192 elems
    const int tid = threadIdx.x, w = tid >> 6, ln = tid & 63;
    const int quad = ln >> 4, c16 = ln & 15;
    // XCD swizzle: 4 bh per XCD, all 16 q-blocks of a bh on one XCD (K/V L2 reuse)
    const int bid = blockIdx.x;
    const int xcd = bid & 7, jj = bid >> 3;
    const int bh = xcd * 4 + (jj >> 4);
    const int qb = jj & 15;
    const int b = bh >> 4, h = bh & 15;

    // Q B-fragments (persistent)
    bf16x8 qf[2][2];
    #pragma unroll
    for (int qsub = 0; qsub < 2; qsub++) {
        const unsigned short* qp = qh + ((size_t)bh * SEQ + qb * 128 + w * 32 + qsub * 16 + c16) * DKH + quad * 8;
        qf[qsub][0] = *(const bf16x8*)qp;
        qf[qsub][1] = *(const bf16x8*)(qp + 32);
    }

    const unsigned short* kT = khs + (size_t)bh * 131072;
    const unsigned short* vT = vts + (size_t)bh * 131072;
    const unsigned short* bb0 = biasf + (((size_t)b * 128 + qb * 8 + w * 2) * 64) * 512 + ln * 8;
    const unsigned short* bb1 = bb0 + 32768;   // qsub stride = 64*512

    f32x4 accv[4][2];
    #pragma unroll
    for (int dt = 0; dt < 4; dt++)
        #pragma unroll
        for (int qsub = 0; qsub < 2; qsub++) accv[dt][qsub] = (f32x4){0.f, 0.f, 0.f, 0.f};
    float lacc[2] = {0.f, 0.f};

    // prefetch tile-0 bias fragments
    bf16x8 bcur[2][4];
    #pragma unroll
    for (int j = 0; j < 4; j++) {
        bcur[0][j] = *(const bf16x8*)(bb0 + j * 512);
        bcur[1][j] = *(const bf16x8*)(bb1 + j * 512);
    }

    for (int T = 0; T < 16; T++) {
        __syncthreads();   // previous tile's ds_reads done
        {
            const unsigned short* ksrc = kT + T * 8192 + w * 512 + ln * 8;
            const unsigned short* vsrc = vT + T * 8192 + w * 512 + ln * 8;
            unsigned short* lk = smem + w * 512;
            unsigned short* lv = smem + 8192 + w * 512;
            #pragma unroll
            for (int p = 0; p < 4; p++) {
                gload16(ksrc + p * 2048, lk + p * 2048);
                gload16(vsrc + p * 2048, lv + p * 2048);
            }
        }
        // next-tile bias into regs (drained by the same barrier)
        bf16x8 bnext[2][4];
        {
            const int Tn = (T < 15) ? T + 1 : 15;
            #pragma unroll
            for (int j = 0; j < 4; j++) {
                bnext[0][j] = *(const bf16x8*)(bb0 + (Tn * 4 + j) * 512);
                bnext[1][j] = *(const bf16x8*)(bb1 + (Tn * 4 + j) * 512);
            }
        }
        __syncthreads();   // drain global_load_lds
        #pragma unroll
        for (int j = 0; j < 4; j++) {
            bf16x8 kf00 = *(const bf16x8*)(smem + j * 2048 + ln * 8);           // ks0 kvs0
            bf16x8 kf01 = *(const bf16x8*)(smem + j * 2048 + 512 + ln * 8);     // ks0 kvs1
            bf16x8 kf10 = *(const bf16x8*)(smem + j * 2048 + 1024 + ln * 8);    // ks1 kvs0
            bf16x8 kf11 = *(const bf16x8*)(smem + j * 2048 + 1536 + ln * 8);    // ks1 kvs1
            bf16x8 vf[4];
            #pragma unroll
            for (int dt = 0; dt < 4; dt++)
                vf[dt] = *(const bf16x8*)(smem + 8192 + j * 2048 + dt * 512 + ln * 8);
            #pragma unroll
            for (int qsub = 0; qsub < 2; qsub++) {
                const unsigned int* bd = (const unsigned int*)&bcur[qsub][j];
                f32x4 s0, s1;
                s0[0] = asfloat(bd[0] << 16); s0[1] = asfloat(bd[0] & 0xFFFF0000u);
                s0[2] = asfloat(bd[1] << 16); s0[3] = asfloat(bd[1] & 0xFFFF0000u);
                s1[0] = asfloat(bd[2] << 16); s1[1] = asfloat(bd[2] & 0xFFFF0000u);
                s1[2] = asfloat(bd[3] << 16); s1[3] = asfloat(bd[3] & 0xFFFF0000u);
                s0 = __builtin_amdgcn_mfma_f32_16x16x32_bf16(kf00, qf[qsub][0], s0, 0, 0, 0);
                s0 = __builtin_amdgcn_mfma_f32_16x16x32_bf16(kf10, qf[qsub][1], s0, 0, 0, 0);
                s1 = __builtin_amdgcn_mfma_f32_16x16x32_bf16(kf01, qf[qsub][0], s1, 0, 0, 0);
                s1 = __builtin_amdgcn_mfma_f32_16x16x32_bf16(kf11, qf[qsub][1], s1, 0, 0, 0);
                #pragma unroll
                for (int r = 0; r < 4; r++) { s0[r] = fexp2(s0[r]); s1[r] = fexp2(s1[r]); }
                lacc[qsub] += ((s0[0] + s0[1]) + (s0[2] + s0[3]))
                            + ((s1[0] + s1[1]) + (s1[2] + s1[3]));
                union { bf16x8 v; __hip_bfloat162 hh[4]; } pu;
                pu.hh[0] = __float22bfloat162_rn(make_float2(s0[0], s0[1]));
                pu.hh[1] = __float22bfloat162_rn(make_float2(s0[2], s0[3]));
                pu.hh[2] = __float22bfloat162_rn(make_float2(s1[0], s1[1]));
                pu.hh[3] = __float22bfloat162_rn(make_float2(s1[2], s1[3]));
                #pragma unroll
                for (int dt = 0; dt < 4; dt++)
                    accv[dt][qsub] = __builtin_amdgcn_mfma_f32_16x16x32_bf16(vf[dt], pu.v, accv[dt][qsub], 0, 0, 0);
            }
            bcur[0][j] = bnext[0][j];
            bcur[1][j] = bnext[1][j];
        }
    }

    // epilogue: normalize, per-wave LDS transpose (reuse smem), coalesced store
    float inv[2];
    #pragma unroll
    for (int qsub = 0; qsub < 2; qsub++) {
        float l = lacc[qsub];
        l += __shfl_xor(l, 16);
        l += __shfl_xor(l, 32);
        inv[qsub] = 1.0f / l;
    }
    __syncthreads();   // all waves done reading staged K/V
    unsigned short* ot = smem + w * 2304;   // 32 x 72 per wave
    #pragma unroll
    for (int dt = 0; dt < 4; dt++)
        #pragma unroll
        for (int qsub = 0; qsub < 2; qsub++)
            #pragma unroll
            for (int r = 0; r < 4; r += 2) {
                union { __hip_bfloat162 hh; unsigned int u; } pk;
                pk.hh = __float22bfloat162_rn(make_float2(accv[dt][qsub][r] * inv[qsub],
                                                         accv[dt][qsub][r + 1] * inv[qsub]));
                *(unsigned int*)&ot[(qsub * 16 + c16) * 72 + dt * 16 + quad * 4 + r] = pk.u;
            }
    // wave-local write->read: in-order per wave, no barrier needed
    const int qrow2 = ln >> 1, half = ln & 1;
    const unsigned short* srcp = ot + qrow2 * 72 + half * 32;
    unsigned short* dstp = ctx + ((size_t)b * SEQ + qb * 128 + w * 32 + qrow2) * HIDDEN
                         + h * 64 + half * 32;
    #pragma unroll
    for (int kk = 0; kk < 4; kk++)
        *(bf16x8*)(dstp + kk * 8) = *(const bf16x8*)(srcp + kk * 8);
}

// ---------------- output projection ----------------
__global__ __launch_bounds__(256, 2) void outproj(const unsigned short* __restrict__ X,
                                                  const unsigned short* __restrict__ Wt,
                                                  const float* __restrict__ bo,
                                                  float* __restrict__ out) {
    __shared__ __align__(16) unsigned short smem[16384];
    const int mbase = blockIdx.x * 128, nbase = blockIdx.y * 128;
    const int tid = threadIdx.x, w = tid >> 6, ln = tid & 63;
    const int qr = (w >> 1) * 64, qc = (w & 1) * 64;
    const int g = ln >> 4, c16 = ln & 15;

    f32x4 acc[4][4];
    gemm_core_128(X, Wt, smem, mbase, nbase, acc);

    float bo_v[4];
    #pragma unroll
    for (int ct = 0; ct < 4; ct++) bo_v[ct] = bo[nbase + qc + ct * 16 + c16];
    #pragma unroll
    for (int rt = 0; rt < 4; rt++)
        #pragma unroll
        for (int ct = 0; ct < 4; ct++)
            #pragma unroll
            for (int r4 = 0; r4 < 4; r4++)
                out[(size_t)(mbase + qr + rt * 16 + g * 4 + r4) * HIDDEN + nbase + qc + ct * 16 + c16]
                    = acc[rt][ct][r4] + bo_v[ct];
}

// ---------------- launch ----------------
extern "C" void kernel_launch(void* const* d_in, const int* in_sizes, int n_in,
                              void* d_out, int out_size, void* d_ws, size_t ws_size,
                              hipStream_t stream) {
    const float* q    = (const float*)d_in[0];
    const float* k    = (const float*)d_in[1];
    const float* v    = (const float*)d_in[2];
    const float* bias = (const float*)d_in[3];
    const float* mask = (const float*)d_in[4];
    const float* Wq   = (const float*)d_in[5];
    const float* bq   = (const float*)d_in[6];
    const float* Wk   = (const float*)d_in[7];
    const float* bk   = (const float*)d_in[8];
    const float* Wv   = (const float*)d_in[9];
    const float* bv   = (const float*)d_in[10];
    const float* Wo   = (const float*)d_in[11];
    const float* bo   = (const float*)d_in[12];

    char* ws = (char*)d_ws;
    unsigned short* qkv_bf = (unsigned short*)(ws);              // 24 MB
    unsigned short* wt     = (unsigned short*)(ws + 25165824);   // 8 MB
    unsigned short* qh     = (unsigned short*)(ws + 33554432);   // 8 MB
    unsigned short* khs    = (unsigned short*)(ws + 41943040);   // 8 MB frag-packed
    unsigned short* vts    = (unsigned short*)(ws + 50331648);   // 8 MB frag-packed
    unsigned short* ctx    = (unsigned short*)(ws + 58720256);   // 8 MB
    unsigned short* biasf  = (unsigned short*)(ws + 67108864);   // 16 MB bf16 frag-tiled
    // total ws use: 83,886,080 bytes

    prep<<<17408, 256, 0, stream>>>((const float4*)q, (const float4*)k, (const float4*)v,
                                    (u16x4*)qkv_bf, Wq, Wk, Wv, Wo, wt, bias, mask, biasf);
    proj_gemm<<<dim3(32, 8, 3), 256, 0, stream>>>(qkv_bf, wt, bq, bk, bv, qh, khs, vts);
    attn<<<512, 256, 0, stream>>>(qh, khs, vts, biasf, ctx);
    outproj<<<dim3(32, 8), 256, 0, stream>>>(ctx, wt + (size_t)3 * HIDDEN * HIDDEN, bo,
                                             (float*)d_out);
}